// Round 2
// baseline (5199.503 us; speedup 1.0000x reference)
//
#include <hip/hip_runtime.h>
#include <hip/hip_bf16.h>
#include <math.h>

// Problem constants
#define NN    128
#define CINc  64
#define COUTc 64
#define CIq   16
#define TTc   128
#define VVc   25
#define SSs   3
#define STt   2
#define BN_EPS 1e-5f
#define LRs   0.1f
#define TV    (TTc * VVc)          // 3200

typedef __hip_bfloat16 bf16;

__device__ __forceinline__ float lrelu(float a) { return a >= 0.f ? a : LRs * a; }
__device__ __forceinline__ float b2f(bf16 x) { return __bfloat162float(x); }
__device__ __forceinline__ bf16  f2b(float x) { return __float2bfloat16(x); }

// ---------------------------------------------------------------------------
// K1a: spatial attention score PARTIALS over a 32-t chunk.
// grid = N*SS*4.  part[(n*SS+s)*4+chunk][p] = sum_{c,t in chunk} q*k  (fp32)
// ---------------------------------------------------------------------------
__global__ __launch_bounds__(256) void k_attn_s_part(
    const float* __restrict__ x, const float* __restrict__ w, const float* __restrict__ b,
    float* __restrict__ part)
{
    const int bx = blockIdx.x;
    const int n = bx / (SSs * 4);
    const int rem = bx % (SSs * 4);
    const int s = rem >> 2, chunk = rem & 3;
    const int tid = threadIdx.x;
    __shared__ float xs[CINc * VVc];
    __shared__ float qs[CIq * VVc];
    __shared__ float ks[CIq * VVc];
    const int qoff = s * CIq;
    const int koff = (SSs + s) * CIq;
    const float* xb = x + (size_t)n * CINc * TV;
    float acc0 = 0.f, acc1 = 0.f, acc2 = 0.f;

    for (int tt = 0; tt < 32; ++tt) {
        const int t = chunk * 32 + tt;
        __syncthreads();
        for (int i = tid; i < CINc * VVc; i += 256)
            xs[i] = xb[(i / VVc) * TV + t * VVc + (i % VVc)];
        __syncthreads();
        for (int i = tid; i < 2 * CIq * VVc; i += 256) {
            const int which = i / (CIq * VVc);
            const int idx = i % (CIq * VVc);
            const int cq = idx / VVc, u = idx % VVc;
            const int row = (which ? koff : qoff) + cq;
            const float* wr = w + row * CINc;
            float a = b[row];
            #pragma unroll 8
            for (int c = 0; c < CINc; ++c) a += wr[c] * xs[c * VVc + u];
            if (which) ks[idx] = a; else qs[idx] = a;
        }
        __syncthreads();
        for (int p = tid; p < VVc * VVc; p += 256) {
            const int u = p / VVc, v = p % VVc;
            float a = 0.f;
            #pragma unroll
            for (int cq = 0; cq < CIq; ++cq) a += qs[cq * VVc + u] * ks[cq * VVc + v];
            const int r = (p - tid) >> 8;
            if (r == 0) acc0 += a; else if (r == 1) acc1 += a; else acc2 += a;
        }
    }
    float* pb = part + ((size_t)(n * SSs + s) * 4 + chunk) * (VVc * VVc);
    for (int p = tid; p < VVc * VVc; p += 256) {
        const int r = (p - tid) >> 8;
        pb[p] = (r == 0) ? acc0 : ((r == 1) ? acc1 : acc2);
    }
}

// K1b: finalize attn = tanh(sum_chunks / (CI*T)) * alpha + att0.  240000 elems.
__global__ __launch_bounds__(256) void k_attn_s_fin(
    const float* __restrict__ part, const float* __restrict__ alphas,
    const float* __restrict__ att0s, float* __restrict__ attn)
{
    const int i = blockIdx.x * 256 + threadIdx.x;
    if (i >= NN * SSs * VVc * VVc) return;
    const int n = i / (SSs * VVc * VVc);
    const int rem = i % (SSs * VVc * VVc);
    const int s = rem / (VVc * VVc), p = rem % (VVc * VVc);
    const float* pb = part + ((size_t)(n * SSs + s) * 4) * (VVc * VVc);
    const float a = pb[p] + pb[VVc * VVc + p] + pb[2 * VVc * VVc + p] + pb[3 * VVc * VVc + p];
    attn[i] = tanhf(a * (1.f / (CIq * TTc))) * alphas[s] + att0s[s * VVc * VVc + p];
}

// ---------------------------------------------------------------------------
// K2: fused spatial block.  grid = N*T.  Writes y (bf16).
// ---------------------------------------------------------------------------
__global__ __launch_bounds__(256) void k_spatial(
    const float* __restrict__ x, const float* __restrict__ attn,
    const float* __restrict__ w_out, const float* __restrict__ b_out, const float* __restrict__ bn_out,
    const float* __restrict__ w_ff,  const float* __restrict__ b_ff,  const float* __restrict__ bn_ff,
    bf16* __restrict__ y)
{
    const int n = blockIdx.x / TTc, t = blockIdx.x % TTc;
    const int tid = threadIdx.x;
    __shared__ float xs[CINc * VVc];
    __shared__ float at[SSs * VVc * VVc];
    __shared__ float ya[SSs * CINc * VVc];
    __shared__ float y1[CINc * VVc];
    __shared__ float sc1[COUTc], sh1[COUTc], sc2[COUTc], sh2[COUTc];

    const float* xb = x + (size_t)n * CINc * TV + t * VVc;
    for (int i = tid; i < CINc * VVc; i += 256)
        xs[i] = xb[(i / VVc) * TV + (i % VVc)];
    for (int i = tid; i < SSs * VVc * VVc; i += 256)
        at[i] = attn[(size_t)n * SSs * VVc * VVc + i];
    if (tid < COUTc) {
        float g = bn_out[tid], bb = bn_out[COUTc + tid], m = bn_out[2 * COUTc + tid], vv = bn_out[3 * COUTc + tid];
        float inv = g * rsqrtf(vv + BN_EPS);
        sc1[tid] = inv; sh1[tid] = (b_out[tid] - m) * inv + bb;
        g = bn_ff[tid]; bb = bn_ff[COUTc + tid]; m = bn_ff[2 * COUTc + tid]; vv = bn_ff[3 * COUTc + tid];
        inv = g * rsqrtf(vv + BN_EPS);
        sc2[tid] = inv; sh2[tid] = (b_ff[tid] - m) * inv + bb;
    }
    __syncthreads();

    for (int i = tid; i < SSs * CINc * VVc; i += 256) {
        const int scv = i / VVc, v = i % VVc;
        const int s = scv / CINc, c = scv % CINc;
        float a = 0.f;
        #pragma unroll
        for (int u = 0; u < VVc; ++u) a += xs[c * VVc + u] * at[s * VVc * VVc + u * VVc + v];
        ya[i] = a;
    }
    __syncthreads();
    for (int i = tid; i < COUTc * VVc; i += 256) {
        const int o = i / VVc, v = i % VVc;
        const float* wr = w_out + o * (SSs * CINc);
        float a = 0.f;
        #pragma unroll 8
        for (int k = 0; k < SSs * CINc; ++k) a += wr[k] * ya[k * VVc + v];
        a = a * sc1[o] + sh1[o] + xs[i];
        y1[i] = lrelu(a);
    }
    __syncthreads();
    bf16* yb = y + (size_t)n * CINc * TV + t * VVc;
    for (int i = tid; i < COUTc * VVc; i += 256) {
        const int o = i / VVc, v = i % VVc;
        const float* wr = w_ff + o * COUTc;
        float a = 0.f;
        #pragma unroll 8
        for (int k = 0; k < COUTc; ++k) a += wr[k] * y1[k * VVc + v];
        a = a * sc2[o] + sh2[o] + xs[i];
        yb[o * TV + v] = f2b(lrelu(a));
    }
}

// ---------------------------------------------------------------------------
// K3: temporal q/k projection (128 out-channels).  grid = N*T.  bf16 out.
// ---------------------------------------------------------------------------
__global__ __launch_bounds__(256) void k_qkt(
    const bf16* __restrict__ y, const float* __restrict__ w, const float* __restrict__ b,
    bf16* __restrict__ qkt)
{
    const int n = blockIdx.x / TTc, t = blockIdx.x % TTc;
    const int tid = threadIdx.x;
    __shared__ float ys[CINc * VVc];
    const bf16* yb = y + (size_t)n * CINc * TV + t * VVc;
    for (int i = tid; i < CINc * VVc; i += 256)
        ys[i] = b2f(yb[(i / VVc) * TV + (i % VVc)]);
    __syncthreads();
    bf16* qb = qkt + (size_t)n * 128 * TV + t * VVc;
    for (int i = tid; i < 128 * VVc; i += 256) {
        const int o = i / VVc, v = i % VVc;
        const float* wr = w + o * CINc;
        float a = b[o];
        #pragma unroll 8
        for (int c = 0; c < CINc; ++c) a += wr[c] * ys[c * VVc + v];
        qb[o * TV + v] = f2b(a);
    }
}

// ---------------------------------------------------------------------------
// K4: temporal attention scores, stored TRANSPOSED bf16: aT[n][ds][q][t].
// grid = N*4*2 (t-range halves).  Zeros written where masked.
// ---------------------------------------------------------------------------
__global__ __launch_bounds__(256) void k_attn_t(
    const bf16* __restrict__ qkt, const float* __restrict__ alphat_f,
    const float* __restrict__ alphat_b, bf16* __restrict__ aT)
{
    const int bx = blockIdx.x;
    const int th = bx & 1;             // t-range half
    const int ds = (bx >> 1) & 3;
    const int n  = bx >> 3;
    const int dir = ds >> 1, s = ds & 1;
    const int qoff = dir * 32 + s * CIq;
    const int koff = 64 + dir * 32 + s * CIq;
    const float alpha = dir ? alphat_b[s] : alphat_f[s];
    const int tid = threadIdx.x, ti = tid >> 4, tj = tid & 15;
    __shared__ float ql[CIq * 16 * VVc];
    __shared__ float kl[CIq * 16 * VVc];
    const bf16* qb = qkt + (size_t)n * 128 * TV;
    bf16* aout = aT + ((size_t)n * 4 + ds) * TTc * TTc;

    for (int t0 = th * 64; t0 < th * 64 + 64; t0 += 16) {
        __syncthreads();
        for (int i = tid; i < CIq * 16 * VVc; i += 256) {
            const int c = i / (16 * VVc), rem = i % (16 * VVc), tt = rem / VVc, v = rem % VVc;
            ql[i] = b2f(qb[(qoff + c) * TV + (t0 + tt) * VVc + v]);
        }
        for (int q0 = 0; q0 < TTc; q0 += 16) {
            const bool any = dir ? (q0 + 15 >= t0) : (q0 <= t0 + 15);
            __syncthreads();
            if (any) {
                for (int i = tid; i < CIq * 16 * VVc; i += 256) {
                    const int c = i / (16 * VVc), rem = i % (16 * VVc), tt = rem / VVc, v = rem % VVc;
                    kl[i] = b2f(qb[(koff + c) * TV + (q0 + tt) * VVc + v]);
                }
            }
            __syncthreads();
            const int t = t0 + ti, q = q0 + tj;
            const bool valid = dir ? (q >= t) : (q <= t);
            float val = 0.f;
            if (any && valid) {
                float a = 0.f;
                for (int c = 0; c < CIq; ++c) {
                    const float* qr = &ql[c * (16 * VVc) + ti * VVc];
                    const float* kr = &kl[c * (16 * VVc) + tj * VVc];
                    #pragma unroll
                    for (int v = 0; v < VVc; ++v) a += qr[v] * kr[v];
                }
                val = tanhf(a * (1.f / 400.f)) * alpha;
            }
            aout[q * TTc + t] = f2b(val);
        }
    }
}

// ---------------------------------------------------------------------------
// K5a: p_ds[n,o,t,v] = sum_c w_out_t[o, base+c] * y[n,c,t,v]   (bf16 out)
// grid = N*T.  base = (ds>>1)*128 + (ds&1)*64.
// ---------------------------------------------------------------------------
__global__ __launch_bounds__(256) void k_pproj(
    const bf16* __restrict__ y, const float* __restrict__ w_out_t,
    int base, bf16* __restrict__ P)
{
    const int n = blockIdx.x / TTc, t = blockIdx.x % TTc;
    const int tid = threadIdx.x;
    __shared__ float ys[CINc * VVc];
    __shared__ float wl[COUTc * CINc];
    const bf16* yb = y + (size_t)n * CINc * TV + t * VVc;
    for (int i = tid; i < CINc * VVc; i += 256)
        ys[i] = b2f(yb[(i / VVc) * TV + (i % VVc)]);
    for (int i = tid; i < COUTc * CINc; i += 256)
        wl[i] = w_out_t[(i >> 6) * 256 + base + (i & 63)];
    __syncthreads();
    bf16* pb = P + (size_t)n * CINc * TV + t * VVc;
    for (int i = tid; i < COUTc * VVc; i += 256) {
        const int o = i / VVc, v = i % VVc;
        float a = 0.f;
        #pragma unroll 8
        for (int c = 0; c < CINc; ++c) a += wl[o * CINc + c] * ys[c * VVc + v];
        pb[o * TV + v] = f2b(a);
    }
}

// ---------------------------------------------------------------------------
// K5b: u[n,o,q,v] (+)= sum_t aT[n,ds,q,t] * p[n,o,t,v].
// grid = N * 8(o-tile of 8) * 4(q-tile of 32).  Masked t-tiles skipped.
// ---------------------------------------------------------------------------
__global__ __launch_bounds__(256) void k_uacc(
    const bf16* __restrict__ P, const bf16* __restrict__ aT,
    int ds, int beta, bf16* __restrict__ U)
{
    const int bx = blockIdx.x;
    const int qt = bx & 3;
    const int ot = (bx >> 2) & 7;
    const int n  = bx >> 5;
    const int q0 = qt * 32;
    const int dir = ds >> 1;
    const int tid = threadIdx.x;
    const int qi = tid & 31, oi = tid >> 5;   // oi in 0..7
    __shared__ float al[32 * 33];
    __shared__ float ps[8 * 32 * VVc];
    const bf16* ab = aT + ((size_t)n * 4 + ds) * TTc * TTc;
    const bf16* pb = P + (size_t)n * CINc * TV;
    float acc[VVc];
    #pragma unroll
    for (int v = 0; v < VVc; ++v) acc[v] = 0.f;

    const int tlo = dir ? 0 : q0;             // b: t<=q ; f: t>=q
    const int thi = dir ? (q0 + 32) : TTc;
    for (int t0 = tlo; t0 < thi; t0 += 32) {
        __syncthreads();
        for (int i = tid; i < 32 * 32; i += 256) {
            const int qq = i >> 5, tt = i & 31;
            al[qq * 33 + tt] = b2f(ab[(size_t)(q0 + qq) * TTc + t0 + tt]);
        }
        for (int i = tid; i < 8 * 32 * VVc; i += 256) {
            const int c = i / (32 * VVc), rem = i % (32 * VVc), tt = rem / VVc, v = rem % VVc;
            ps[i] = b2f(pb[(ot * 8 + c) * TV + (t0 + tt) * VVc + v]);
        }
        __syncthreads();
        for (int tt = 0; tt < 32; ++tt) {
            const float av = al[qi * 33 + tt];
            const float* pr = &ps[oi * (32 * VVc) + tt * VVc];
            #pragma unroll
            for (int v = 0; v < VVc; ++v) acc[v] += av * pr[v];
        }
    }
    bf16* ub = U + (size_t)n * CINc * TV + (ot * 8 + oi) * TV + (q0 + qi) * VVc;
    if (beta) {
        #pragma unroll
        for (int v = 0; v < VVc; ++v) ub[v] = f2b(acc[v] + b2f(ub[v]));
    } else {
        #pragma unroll
        for (int v = 0; v < VVc; ++v) ub[v] = f2b(acc[v]);
    }
}

// ---------------------------------------------------------------------------
// K5c: fused temporal 1x1 blocks.  u already has Wout_t applied.
// z1 = lrelu(y + u*sc1+sh1);  z = lrelu(y + BN(Wff_t@z1)).  z over y in-place.
// ---------------------------------------------------------------------------
__global__ __launch_bounds__(256) void k_temporal(
    const bf16* __restrict__ U, bf16* __restrict__ y,
    const float* __restrict__ b_out, const float* __restrict__ bn_out,
    const float* __restrict__ w_ff, const float* __restrict__ b_ff, const float* __restrict__ bn_ff)
{
    const int n = blockIdx.x / TTc, q = blockIdx.x % TTc;
    const int tid = threadIdx.x;
    __shared__ float ys[CINc * VVc];
    __shared__ float z1[CINc * VVc];
    __shared__ float wl[COUTc * CINc];
    __shared__ float sc1[COUTc], sh1[COUTc], sc2[COUTc], sh2[COUTc];

    const bf16* ub = U + (size_t)n * CINc * TV + q * VVc;
    bf16* yb = y + (size_t)n * CINc * TV + q * VVc;
    for (int i = tid; i < CINc * VVc; i += 256)
        ys[i] = b2f(yb[(i / VVc) * TV + (i % VVc)]);
    for (int i = tid; i < COUTc * CINc; i += 256)
        wl[i] = w_ff[i];
    if (tid < COUTc) {
        float g = bn_out[tid], bb = bn_out[COUTc + tid], m = bn_out[2 * COUTc + tid], vv = bn_out[3 * COUTc + tid];
        float inv = g * rsqrtf(vv + BN_EPS);
        sc1[tid] = inv; sh1[tid] = (b_out[tid] - m) * inv + bb;
        g = bn_ff[tid]; bb = bn_ff[COUTc + tid]; m = bn_ff[2 * COUTc + tid]; vv = bn_ff[3 * COUTc + tid];
        inv = g * rsqrtf(vv + BN_EPS);
        sc2[tid] = inv; sh2[tid] = (b_ff[tid] - m) * inv + bb;
    }
    __syncthreads();
    for (int i = tid; i < COUTc * VVc; i += 256) {
        const int o = i / VVc;
        const float uv = b2f(ub[o * TV + (i % VVc)]);
        z1[i] = lrelu(ys[i] + uv * sc1[o] + sh1[o]);
    }
    __syncthreads();
    for (int i = tid; i < COUTc * VVc; i += 256) {
        const int o = i / VVc, v = i % VVc;
        float a = 0.f;
        #pragma unroll 8
        for (int k = 0; k < COUTc; ++k) a += wl[o * COUTc + k] * z1[k * VVc + v];
        a = a * sc2[o] + sh2[o] + ys[i];
        yb[o * TV + v] = f2b(lrelu(a));
    }
}

// ---------------------------------------------------------------------------
// K6: 7x1 temporal conv + BN + residual + lrelu -> out (fp32).
// grid = N * 32; block covers 4 t's.
// ---------------------------------------------------------------------------
__global__ __launch_bounds__(256) void k_tcn(
    const bf16* __restrict__ z, const float* __restrict__ w, const float* __restrict__ b,
    const float* __restrict__ bn, float* __restrict__ out)
{
    const int n = blockIdx.x >> 5, t0 = (blockIdx.x & 31) * 4;
    const int tid = threadIdx.x;
    const int o = tid >> 2, tl = tid & 3;
    __shared__ float zs[CINc * 10 * VVc];   // 62.5 KB
    __shared__ float sc[COUTc], sh[COUTc];
    const bf16* zb = z + (size_t)n * CINc * TV;
    for (int i = tid; i < CINc * 10 * VVc; i += 256) {
        const int c = i / (10 * VVc), rem = i % (10 * VVc), tt = rem / VVc, v = rem % VVc;
        const int t = t0 - 3 + tt;
        zs[i] = (t >= 0 && t < TTc) ? b2f(zb[c * TV + t * VVc + v]) : 0.f;
    }
    if (tid < COUTc) {
        const float g = bn[tid], bb = bn[COUTc + tid], m = bn[2 * COUTc + tid], vv = bn[3 * COUTc + tid];
        const float inv = g * rsqrtf(vv + BN_EPS);
        sc[tid] = inv; sh[tid] = (b[tid] - m) * inv + bb;
    }
    __syncthreads();

    float acc[VVc];
    #pragma unroll
    for (int v = 0; v < VVc; ++v) acc[v] = 0.f;
    for (int c = 0; c < CINc; ++c) {
        const float* wr = w + (o * CINc + c) * 7;
        const float* zr = &zs[c * (10 * VVc)];
        #pragma unroll
        for (int dt = 0; dt < 7; ++dt) {
            const float wv = wr[dt];
            const float* zp = zr + (tl + dt) * VVc;
            #pragma unroll
            for (int v = 0; v < VVc; ++v) acc[v] += wv * zp[v];
        }
    }
    float* ob = out + (size_t)n * CINc * TV + o * TV + (t0 + tl) * VVc;
    const float* zres = &zs[o * (10 * VVc) + (tl + 3) * VVc];
    #pragma unroll
    for (int v = 0; v < VVc; ++v)
        ob[v] = lrelu(acc[v] * sc[o] + sh[o] + zres[v]);
}

// ---------------------------------------------------------------------------
// Workspace (byte offsets), total 179,306,496 B:
//   part_s f32 : 0          (3.84 MB used, 4 MB reserved)
//   attn   f32 : 4,194,304  (0.96 MB used, 1 MB reserved)
//   aT     bf16: 5,242,880  (16.78 MB)
//   Y      bf16: 22,020,096 (52.43 MB)  — later holds z in-place
//   R          : 74,448,896 (104.86 MB): first qkt bf16 (full);
//                after k_attn_t reused as P bf16 (52.43) + U bf16 (52.43)
// ---------------------------------------------------------------------------
extern "C" void kernel_launch(void* const* d_in, const int* in_sizes, int n_in,
                              void* d_out, int out_size, void* d_ws, size_t ws_size,
                              hipStream_t stream) {
    const float* x        = (const float*)d_in[0];
    const float* w_in_s   = (const float*)d_in[1];
    const float* b_in_s   = (const float*)d_in[2];
    const float* alphas   = (const float*)d_in[3];
    const float* att0s    = (const float*)d_in[4];
    const float* w_out_s  = (const float*)d_in[5];
    const float* b_out_s  = (const float*)d_in[6];
    const float* bn_out_s = (const float*)d_in[7];
    const float* w_ff_s   = (const float*)d_in[8];
    const float* b_ff_s   = (const float*)d_in[9];
    const float* bn_ff_s  = (const float*)d_in[10];
    const float* w_in_t   = (const float*)d_in[11];
    const float* b_in_t   = (const float*)d_in[12];
    const float* alphat_f = (const float*)d_in[13];
    const float* alphat_b = (const float*)d_in[14];
    const float* w_out_t  = (const float*)d_in[15];
    const float* b_out_t  = (const float*)d_in[16];
    const float* bn_out_t = (const float*)d_in[17];
    const float* w_ff_t   = (const float*)d_in[18];
    const float* b_ff_t   = (const float*)d_in[19];
    const float* bn_ff_t  = (const float*)d_in[20];
    const float* w_tcn    = (const float*)d_in[21];
    const float* b_tcn    = (const float*)d_in[22];
    const float* bn_tcn   = (const float*)d_in[23];
    float* out = (float*)d_out;
    char* ws = (char*)d_ws;

    float* part_s = (float*)(ws + 0);
    float* attn   = (float*)(ws + 4194304);
    bf16*  aT     = (bf16*)(ws + 5242880);
    bf16*  Y      = (bf16*)(ws + 22020096);
    bf16*  qkt    = (bf16*)(ws + 74448896);
    bf16*  P      = (bf16*)(ws + 74448896);
    bf16*  U      = (bf16*)(ws + 74448896 + 52428800);

    // Stage S
    k_attn_s_part<<<NN * SSs * 4, 256, 0, stream>>>(x, w_in_s, b_in_s, part_s);
    k_attn_s_fin<<<(NN * SSs * VVc * VVc + 255) / 256, 256, 0, stream>>>(part_s, alphas, att0s, attn);
    k_spatial<<<NN * TTc, 256, 0, stream>>>(x, attn, w_out_s, b_out_s, bn_out_s,
                                            w_ff_s, b_ff_s, bn_ff_s, Y);
    // Stage T scores
    k_qkt<<<NN * TTc, 256, 0, stream>>>(Y, w_in_t, b_in_t, qkt);
    k_attn_t<<<NN * 4 * 2, 256, 0, stream>>>(qkt, alphat_f, alphat_b, aT);
    // Stage T apply: u = sum_ds a_ds @ (W_ds y)
    for (int ds = 0; ds < 4; ++ds) {
        const int base = (ds >> 1) * 128 + (ds & 1) * 64;
        k_pproj<<<NN * TTc, 256, 0, stream>>>(Y, w_out_t, base, P);
        k_uacc<<<NN * 8 * 4, 256, 0, stream>>>(P, aT, ds, ds ? 1 : 0, U);
    }
    k_temporal<<<NN * TTc, 256, 0, stream>>>(U, Y, b_out_t, bn_out_t,
                                             w_ff_t, b_ff_t, bn_ff_t);
    // TCN epilogue
    k_tcn<<<NN * 32, 256, 0, stream>>>(Y, w_tcn, b_tcn, bn_tcn, out);
}

// Round 3
// 1505.393 us; speedup vs baseline: 3.4539x; 3.4539x over previous
//
#include <hip/hip_runtime.h>
#include <math.h>

#define NN   128
#define TTc  128
#define VVc  25
#define TV   3200
#define BN_EPS 1e-5f

typedef __attribute__((ext_vector_type(8))) short bf8;   // 8 bf16 in 4 VGPRs
typedef __attribute__((ext_vector_type(4))) short s4;    // 4 bf16 (b64)
typedef __attribute__((ext_vector_type(4))) float f4;    // MFMA accumulator

#define MFMA(a,b,c) __builtin_amdgcn_mfma_f32_16x16x32_bf16(a,b,c,0,0,0)

__device__ __forceinline__ float lrelu(float a){ return a>=0.f ? a : 0.1f*a; }
__device__ __forceinline__ short f2bs(float f){
    union{float f; unsigned u;} x; x.f = f;
    unsigned r = x.u + 0x7FFF + ((x.u>>16)&1);
    return (short)(r>>16);
}
__device__ __forceinline__ float b2f(short s){
    union{unsigned u; float f;} x; x.u = ((unsigned)(unsigned short)s)<<16; return x.f;
}
__device__ __forceinline__ s4 packf4(float a,float b,float c,float d){
    s4 r; r.x=f2bs(a); r.y=f2bs(b); r.z=f2bs(c); r.w=f2bs(d); return r;
}

// ---------------------------------------------------------------------------
// Workspace element/byte offsets (total 178,952,192 B; round-2 used 179.3MB OK)
//  wb   (bf16 weights)   : byte 0         (160KB used / 256KB resv)
//  part (f32)            : byte 262144    (3.84 MB)
//  attnB(bf16 [n][32v][96]): byte 4102144 (786 KB)
//  Y    (bf16 [n][3200][64]): byte 4888576 (52.43 MB)
//  aT   (bf16 [n][4][128q][128t]): byte 57317376 (16.78 MB)
//  R    : byte 74094592 (104.86 MB): XB -> QKT -> (PT 52.43 | U 52.43)
// wb element offsets: w_in_s 0 [96][64]; w_out_s 6144 [64][192]; w_ff_s 18432
//  [64][64]; w_in_t 22528 [128][64]; w_out_t 30720 [64][256]; w_ff_t 47104
//  [64][64]; wt 51200 [64][448] (o, dt*64+c)
// ---------------------------------------------------------------------------

__global__ __launch_bounds__(256) void k_prep(
    const float* __restrict__ w_in_s, const float* __restrict__ w_out_s,
    const float* __restrict__ w_ff_s, const float* __restrict__ w_in_t,
    const float* __restrict__ w_out_t, const float* __restrict__ w_ff_t,
    const float* __restrict__ w_tcn, short* __restrict__ wb)
{
    const int total = 51200 + 64*448;
    for (int i = blockIdx.x*256 + threadIdx.x; i < total; i += gridDim.x*256) {
        float v;
        if      (i < 6144)  v = w_in_s[i];
        else if (i < 18432) v = w_out_s[i-6144];
        else if (i < 22528) v = w_ff_s[i-18432];
        else if (i < 30720) v = w_in_t[i-22528];
        else if (i < 47104) v = w_out_t[i-30720];
        else if (i < 51200) v = w_ff_t[i-47104];
        else { int j=i-51200; int o=j/448; int r=j%448; int dt=r>>6; int c=r&63;
               v = w_tcn[(o*64+c)*7 + dt]; }
        wb[i] = f2bs(v);
    }
}

// x f32 [n][c][t][v] -> XB bf16 pixel-major [n][t*25+v][64]
__global__ __launch_bounds__(256) void k_x2b(const float* __restrict__ x, short* __restrict__ XB)
{
    const int n = blockIdx.x >> 4, tc = blockIdx.x & 15, t0 = tc*8;
    const int tid = threadIdx.x;
    __shared__ float xs[64][201];
    const float* xb = x + (size_t)n*204800 + t0*25;
    for (int i = tid; i < 64*200; i += 256) { int c=i/200, p=i%200; xs[c][p] = xb[(size_t)c*3200 + p]; }
    __syncthreads();
    short* ob = XB + (size_t)n*204800 + t0*25*64;
    for (int i = tid; i < 200*64; i += 256) { int p=i>>6, c=i&63; ob[i] = f2bs(xs[c][p]); }
}

// ----- spatial attention scores: partials (VALU, unchanged from round 2) -----
__global__ __launch_bounds__(256) void k_attn_s_part(
    const float* __restrict__ x, const float* __restrict__ w, const float* __restrict__ b,
    float* __restrict__ part)
{
    const int bx = blockIdx.x;
    const int n = bx / 12, rem = bx % 12, s = rem >> 2, chunk = rem & 3;
    const int tid = threadIdx.x;
    __shared__ float xs[64*25];
    __shared__ float qs[16*25];
    __shared__ float ks[16*25];
    const int qoff = s*16, koff = 48 + s*16;
    const float* xb = x + (size_t)n*204800;
    float acc0=0.f, acc1=0.f, acc2=0.f;
    for (int tt = 0; tt < 32; ++tt) {
        const int t = chunk*32 + tt;
        __syncthreads();
        for (int i = tid; i < 64*25; i += 256)
            xs[i] = xb[(i/25)*3200 + t*25 + (i%25)];
        __syncthreads();
        for (int i = tid; i < 2*16*25; i += 256) {
            const int which = i/400, idx = i%400, cq = idx/25, u = idx%25;
            const int row = (which ? koff : qoff) + cq;
            const float* wr = w + row*64;
            float a = b[row];
            #pragma unroll 8
            for (int c = 0; c < 64; ++c) a += wr[c]*xs[c*25+u];
            if (which) ks[idx]=a; else qs[idx]=a;
        }
        __syncthreads();
        for (int p = tid; p < 625; p += 256) {
            const int u=p/25, v=p%25;
            float a = 0.f;
            #pragma unroll
            for (int cq = 0; cq < 16; ++cq) a += qs[cq*25+u]*ks[cq*25+v];
            const int r = (p-tid)>>8;
            if (r==0) acc0+=a; else if (r==1) acc1+=a; else acc2+=a;
        }
    }
    float* pb = part + ((size_t)(n*3+s)*4 + chunk)*625;
    for (int p = tid; p < 625; p += 256) {
        const int r = (p-tid)>>8;
        pb[p] = (r==0)?acc0:((r==1)?acc1:acc2);
    }
}

// finalize -> attnB bf16 [n][32v][96] : attnB[v][s*32+u] = attn[s][u][v], zero-padded
__global__ __launch_bounds__(256) void k_attn_s_fin(
    const float* __restrict__ part, const float* __restrict__ alphas,
    const float* __restrict__ att0s, short* __restrict__ attnB)
{
    const int i = blockIdx.x*256 + threadIdx.x;
    if (i >= NN*32*96) return;
    const int n = i/(32*96), r = i%(32*96), v = r/96, j = r%96, s = j>>5, u = j&31;
    float val = 0.f;
    if (u < 25 && v < 25) {
        const int p = u*25+v;
        const float* pb = part + (size_t)(n*3+s)*4*625;
        const float a = pb[p]+pb[625+p]+pb[1250+p]+pb[1875+p];
        val = tanhf(a*(1.f/2048.f))*alphas[s] + att0s[s*625+p];
    }
    attnB[i] = f2bs(val);
}

// ---------------------------------------------------------------------------
// fused spatial block (MFMA). block=(n, t-chunk4), wave w owns t=t0+w.
// GEMM-A: G_s[u][o]=sum_c x[t,u,c]*Wout[o][s64+c]  -> gsT[o][s32+u]
// GEMM-B: y1pre[o][v]=sum_{s,u} gsT[o][s32+u]*attnB[v][s32+u]; +BN+res+lrelu
// GEMM-C: y[o][v]=Wff@y1; +BN+res+lrelu -> Y global (b64 per lane)
// ---------------------------------------------------------------------------
__global__ __launch_bounds__(256) void k_spatial(
    const short* __restrict__ XB, const short* __restrict__ attnB, const short* __restrict__ wb,
    const float* __restrict__ b_out, const float* __restrict__ bn_out,
    const float* __restrict__ b_ff,  const float* __restrict__ bn_ff,
    short* __restrict__ Y)
{
    const int n = blockIdx.x >> 5, tc = blockIdx.x & 31, t0 = tc*4;
    const int tid = threadIdx.x;
    const int w = tid>>6, lane = tid&63, lr = lane&15, lq = lane>>4;
    __shared__ short xs[4][32][72];
    __shared__ short wlo[64][200];
    __shared__ short wlf[64][72];
    __shared__ short ab[32][104];
    __shared__ short gsT[4][64][104];
    __shared__ short y1[4][32][72];
    __shared__ float sc1s[64], sh1s[64], sc2s[64], sh2s[64];

    // stage xs (zero u-pads)
    for (int i = tid; i < 4*32*8; i += 256) {
        const int row = i>>3, seg = i&7, tl = row>>5, uv = row&31;
        bf8 val = {0,0,0,0,0,0,0,0};
        if (uv < 25) val = *(const bf8*)&XB[((size_t)n*3200 + (t0+tl)*25 + uv)*64 + seg*8];
        *(bf8*)&xs[tl][uv][seg*8] = val;
    }
    for (int i = tid; i < 64*24; i += 256) {   // wlo: 192 = 24 segs
        const int o = i/24, seg = i%24;
        *(bf8*)&wlo[o][seg*8] = *(const bf8*)&wb[6144 + o*192 + seg*8];
    }
    for (int i = tid; i < 64*8; i += 256) {
        const int o = i>>3, seg = i&7;
        *(bf8*)&wlf[o][seg*8] = *(const bf8*)&wb[18432 + o*64 + seg*8];
    }
    for (int i = tid; i < 32*12; i += 256) {   // ab: 96 = 12 segs
        const int v = i/12, seg = i%12;
        *(bf8*)&ab[v][seg*8] = *(const bf8*)&attnB[(size_t)n*3072 + v*96 + seg*8];
    }
    if (tid < 64) {
        float g=bn_out[tid], bb=bn_out[64+tid], m=bn_out[128+tid], vv=bn_out[192+tid];
        float inv = g*rsqrtf(vv+BN_EPS);
        sc1s[tid]=inv; sh1s[tid]=(b_out[tid]-m)*inv+bb;
        g=bn_ff[tid]; bb=bn_ff[64+tid]; m=bn_ff[128+tid]; vv=bn_ff[192+tid];
        inv = g*rsqrtf(vv+BN_EPS);
        sc2s[tid]=inv; sh2s[tid]=(b_ff[tid]-m)*inv+bb;
    }
    __syncthreads();

    const int t = t0 + w;
    // GEMM-A
    for (int s = 0; s < 3; ++s) {
        for (int mt = 0; mt < 2; ++mt) {
            const bf8 a0 = *(const bf8*)&xs[w][mt*16+lr][lq*8];
            const bf8 a1 = *(const bf8*)&xs[w][mt*16+lr][32+lq*8];
            for (int nt = 0; nt < 4; ++nt) {
                f4 acc = {0.f,0.f,0.f,0.f};
                const bf8 b0 = *(const bf8*)&wlo[nt*16+lr][s*64 + lq*8];
                const bf8 b1 = *(const bf8*)&wlo[nt*16+lr][s*64 + 32 + lq*8];
                acc = MFMA(a0,b0,acc); acc = MFMA(a1,b1,acc);
                const int o = nt*16+lr, u0 = mt*16+lq*4;
                *(s4*)&gsT[w][o][s*32+u0] = packf4(acc.x,acc.y,acc.z,acc.w);
            }
        }
    }
    // GEMM-B
    for (int mt = 0; mt < 4; ++mt) {
        const bf8 a0 = *(const bf8*)&gsT[w][mt*16+lr][lq*8];
        const bf8 a1 = *(const bf8*)&gsT[w][mt*16+lr][32+lq*8];
        const bf8 a2 = *(const bf8*)&gsT[w][mt*16+lr][64+lq*8];
        for (int nt = 0; nt < 2; ++nt) {
            f4 acc = {0.f,0.f,0.f,0.f};
            const bf8 b0 = *(const bf8*)&ab[nt*16+lr][lq*8];
            const bf8 b1 = *(const bf8*)&ab[nt*16+lr][32+lq*8];
            const bf8 b2 = *(const bf8*)&ab[nt*16+lr][64+lq*8];
            acc = MFMA(a0,b0,acc); acc = MFMA(a1,b1,acc); acc = MFMA(a2,b2,acc);
            const int v = nt*16+lr, o0 = mt*16+lq*4;
            const s4 xr = *(const s4*)&xs[w][v][o0];
            const float r0 = lrelu(acc.x*sc1s[o0  ]+sh1s[o0  ]+b2f(xr.x));
            const float r1 = lrelu(acc.y*sc1s[o0+1]+sh1s[o0+1]+b2f(xr.y));
            const float r2 = lrelu(acc.z*sc1s[o0+2]+sh1s[o0+2]+b2f(xr.z));
            const float r3 = lrelu(acc.w*sc1s[o0+3]+sh1s[o0+3]+b2f(xr.w));
            *(s4*)&y1[w][v][o0] = packf4(r0,r1,r2,r3);
        }
    }
    // GEMM-C
    for (int mt = 0; mt < 4; ++mt) {
        const bf8 a0 = *(const bf8*)&wlf[mt*16+lr][lq*8];
        const bf8 a1 = *(const bf8*)&wlf[mt*16+lr][32+lq*8];
        for (int nt = 0; nt < 2; ++nt) {
            f4 acc = {0.f,0.f,0.f,0.f};
            const bf8 b0 = *(const bf8*)&y1[w][nt*16+lr][lq*8];
            const bf8 b1 = *(const bf8*)&y1[w][nt*16+lr][32+lq*8];
            acc = MFMA(a0,b0,acc); acc = MFMA(a1,b1,acc);
            const int v = nt*16+lr, o0 = mt*16+lq*4;
            if (v < 25) {
                const s4 xr = *(const s4*)&xs[w][v][o0];
                const float r0 = lrelu(acc.x*sc2s[o0  ]+sh2s[o0  ]+b2f(xr.x));
                const float r1 = lrelu(acc.y*sc2s[o0+1]+sh2s[o0+1]+b2f(xr.y));
                const float r2 = lrelu(acc.z*sc2s[o0+2]+sh2s[o0+2]+b2f(xr.z));
                const float r3 = lrelu(acc.w*sc2s[o0+3]+sh2s[o0+3]+b2f(xr.w));
                *(s4*)&Y[((size_t)n*3200 + t*25 + v)*64 + o0] = packf4(r0,r1,r2,r3);
            }
        }
    }
}

// temporal q/k proj -> QKT bf16 [n][t][128oc][25v]
__global__ __launch_bounds__(256) void k_qkt(
    const short* __restrict__ Y, const short* __restrict__ wb,
    const float* __restrict__ b_in_t, short* __restrict__ qkt)
{
    const int n = blockIdx.x >> 5, tc = blockIdx.x & 31, t0 = tc*4;
    const int tid = threadIdx.x;
    const int w = tid>>6, lane = tid&63, lr = lane&15, lq = lane>>4;
    __shared__ short ys[4][32][72];
    __shared__ short wi[128][72];
    for (int i = tid; i < 4*32*8; i += 256) {
        const int row = i>>3, seg = i&7, tl = row>>5, v = row&31;
        bf8 val = {0,0,0,0,0,0,0,0};
        if (v < 25) val = *(const bf8*)&Y[((size_t)n*3200 + (t0+tl)*25 + v)*64 + seg*8];
        *(bf8*)&ys[tl][v][seg*8] = val;
    }
    for (int i = tid; i < 128*8; i += 256) {
        const int o = i>>3, seg = i&7;
        *(bf8*)&wi[o][seg*8] = *(const bf8*)&wb[22528 + o*64 + seg*8];
    }
    __syncthreads();
    for (int mi = 0; mi < 2; ++mi) {
        const int mt = w*2+mi, tl = mt>>1, vh = mt&1;
        const bf8 a0 = *(const bf8*)&ys[tl][vh*16+lr][lq*8];
        const bf8 a1 = *(const bf8*)&ys[tl][vh*16+lr][32+lq*8];
        for (int nt = 0; nt < 8; ++nt) {
            f4 acc = {0.f,0.f,0.f,0.f};
            const bf8 b0 = *(const bf8*)&wi[nt*16+lr][lq*8];
            const bf8 b1 = *(const bf8*)&wi[nt*16+lr][32+lq*8];
            acc = MFMA(a0,b0,acc); acc = MFMA(a1,b1,acc);
            const int oc = nt*16+lr, v0 = vh*16+lq*4, t = t0+tl;
            const float bias = b_in_t[oc];
            const size_t base = (size_t)n*409600 + (size_t)t*3200 + oc*25 + v0;
            if (v0 < 24)
                *(s4*)&qkt[base] = packf4(acc.x+bias, acc.y+bias, acc.z+bias, acc.w+bias);
            else if (v0 == 24)
                qkt[base] = f2bs(acc.x+bias);
        }
    }
}

// temporal scores -> aT bf16 [n][ds][q][t] (zeros in masked region)
__global__ __launch_bounds__(256) void k_score_t(
    const short* __restrict__ qkt, const float* __restrict__ alphat_f,
    const float* __restrict__ alphat_b, short* __restrict__ aT)
{
    const int n = blockIdx.x >> 2, ds = blockIdx.x & 3, dir = ds>>1, s = ds&1;
    const int qoff = dir*32 + s*16, koff = 64 + dir*32 + s*16;
    const float alpha = dir ? alphat_b[s] : alphat_f[s];
    const int tid = threadIdx.x, w = tid>>6, lane = tid&63, lr = lane&15, lq = lane>>4;
    const short* qb = qkt + (size_t)n*409600;
    short* ao = aT + (size_t)(n*4+ds)*16384;
    const bf8 zf = {0,0,0,0,0,0,0,0};
    for (int ni = 0; ni < 2; ++ni) {
        const int nt = w*2+ni;
        for (int mt = 0; mt < 8; ++mt) {
            const int q = nt*16+lr, t0r = mt*16+lq*4;
            const bool skip = (dir==0) ? (mt < nt) : (mt > nt);
            if (skip) { s4 z = {0,0,0,0}; *(s4*)&ao[q*128 + t0r] = z; continue; }
            f4 acc = {0.f,0.f,0.f,0.f};
            for (int ks = 0; ks < 13; ++ks) {
                bf8 af, bf;
                if (ks==12 && lq>=2) { af = zf; bf = zf; }
                else {
                    af = *(const bf8*)&qb[(size_t)(mt*16+lr)*3200 + qoff*25 + ks*32 + lq*8];
                    bf = *(const bf8*)&qb[(size_t)(nt*16+lr)*3200 + koff*25 + ks*32 + lq*8];
                }
                acc = MFMA(af, bf, acc);
            }
            float r[4];
            #pragma unroll
            for (int j = 0; j < 4; ++j) {
                const int tt = t0r + j;
                const bool ok = (dir==0) ? (tt >= q) : (tt <= q);
                const float a = (j==0)?acc.x:((j==1)?acc.y:((j==2)?acc.z:acc.w));
                r[j] = ok ? tanhf(a*(1.f/400.f))*alpha : 0.f;
            }
            *(s4*)&ao[q*128 + t0r] = packf4(r[0],r[1],r[2],r[3]);
        }
    }
}

// pproj (per ds): PT[v][o][t] = sum_c Y[t,v,c]*w_out_t[o][ds*64+c]
__global__ __launch_bounds__(256) void k_pproj(
    const short* __restrict__ Y, const short* __restrict__ wb,
    int ds, short* __restrict__ PT)
{
    const int n = blockIdx.x / 13, vb = blockIdx.x % 13, v0 = vb*2;
    const int tid = threadIdx.x, w = tid>>6, lane = tid&63, lr = lane&15, lq = lane>>4;
    __shared__ short ys[2][128][72];
    __shared__ short wo[64][72];
    for (int i = tid; i < 2*128*8; i += 256) {
        const int row = i>>3, seg = i&7, vl = row>>7, t = row&127, v = v0+vl;
        bf8 val = {0,0,0,0,0,0,0,0};
        if (v < 25) val = *(const bf8*)&Y[((size_t)n*3200 + t*25 + v)*64 + seg*8];
        *(bf8*)&ys[vl][t][seg*8] = val;
    }
    for (int i = tid; i < 64*8; i += 256) {
        const int o = i>>3, seg = i&7;
        *(bf8*)&wo[o][seg*8] = *(const bf8*)&wb[30720 + o*256 + ds*64 + seg*8];
    }
    __syncthreads();
    for (int mi = 0; mi < 4; ++mi) {
        const int mt = w*4+mi, vl = mt>>3, tt = mt&7;
        const bf8 a0 = *(const bf8*)&ys[vl][tt*16+lr][lq*8];
        const bf8 a1 = *(const bf8*)&ys[vl][tt*16+lr][32+lq*8];
        for (int nt = 0; nt < 4; ++nt) {
            f4 acc = {0.f,0.f,0.f,0.f};
            const bf8 b0 = *(const bf8*)&wo[nt*16+lr][lq*8];
            const bf8 b1 = *(const bf8*)&wo[nt*16+lr][32+lq*8];
            acc = MFMA(a0,b0,acc); acc = MFMA(a1,b1,acc);
            const int o = nt*16+lr, t0r = tt*16+lq*4, v = v0+vl;
            if (v < 25)
                *(s4*)&PT[((size_t)(n*25+v)*64 + o)*128 + t0r] = packf4(acc.x,acc.y,acc.z,acc.w);
        }
    }
}

// uacc (per ds): U[q][v][o] (+)= sum_t PT[v][o][t]*aT[q][t]   (bf16 RMW)
__global__ __launch_bounds__(256) void k_uacc(
    const short* __restrict__ PT, const short* __restrict__ aT,
    int ds, int beta, short* __restrict__ U)
{
    const int n = blockIdx.x >> 2, Q = blockIdx.x & 3;
    const int dir = ds >> 1;
    const int tid = threadIdx.x, w = tid>>6, lane = tid&63, lr = lane&15, lq = lane>>4;
    __shared__ short pts[400][136];
    __shared__ short ats[128][136];
    for (int i = tid; i < 400*16; i += 256) {
        const int r = i>>4, seg = i&15;
        *(bf8*)&pts[r][seg*8] =
            *(const bf8*)&PT[((size_t)n*1600 + Q*400 + r)*128 + seg*8];
    }
    for (int i = tid; i < 128*16; i += 256) {
        const int q = i>>4, seg = i&15;
        *(bf8*)&ats[q][seg*8] =
            *(const bf8*)&aT[(size_t)(n*4+ds)*16384 + q*128 + seg*8];
    }
    __syncthreads();
    const int m_lo = w*7, m_hi = (m_lo+7 < 25) ? m_lo+7 : 25;
    for (int mt = m_lo; mt < m_hi; ++mt) {
        for (int nt = 0; nt < 8; ++nt) {
            f4 acc = {0.f,0.f,0.f,0.f};
            for (int ks = 0; ks < 4; ++ks) {
                const bool skip = (dir==0) ? (ks*32+31 < nt*16) : (ks*32 > nt*16+15);
                if (skip) continue;
                const bf8 af = *(const bf8*)&pts[mt*16+lr][ks*32+lq*8];
                const bf8 bf = *(const bf8*)&ats[nt*16+lr][ks*32+lq*8];
                acc = MFMA(af, bf, acc);
            }
            const int q = nt*16+lr, m0 = mt*16+lq*4;
            const int gr = Q*400 + m0, v = gr>>6, o0 = gr&63;
            short* dst = U + ((size_t)(n*128+q)*25 + v)*64 + o0;
            if (beta) {
                const s4 old = *(const s4*)dst;
                acc.x += b2f(old.x); acc.y += b2f(old.y);
                acc.z += b2f(old.z); acc.w += b2f(old.w);
            }
            *(s4*)dst = packf4(acc.x,acc.y,acc.z,acc.w);
        }
    }
}

// temporal ff block: z1 = lrelu(y + u*sc1+sh1); Y = lrelu(y + BN(Wff@z1)) in-place
__global__ __launch_bounds__(256) void k_temporal(
    const short* __restrict__ U, short* __restrict__ Y, const short* __restrict__ wb,
    const float* __restrict__ b_out, const float* __restrict__ bn_out,
    const float* __restrict__ b_ff,  const float* __restrict__ bn_ff)
{
    const int n = blockIdx.x >> 5, qc = blockIdx.x & 31, q0 = qc*4;
    const int tid = threadIdx.x, w = tid>>6, lane = tid&63, lr = lane&15, lq = lane>>4;
    __shared__ short zs[112][72];
    __shared__ short z1[112][72];
    __shared__ short zout[112][72];
    __shared__ short wf[64][72];
    __shared__ float sc1s[64], sh1s[64], sc2s[64], sh2s[64];
    if (tid < 64) {
        float g=bn_out[tid], bb=bn_out[64+tid], m=bn_out[128+tid], vv=bn_out[192+tid];
        float inv = g*rsqrtf(vv+BN_EPS);
        sc1s[tid]=inv; sh1s[tid]=(b_out[tid]-m)*inv+bb;
        g=bn_ff[tid]; bb=bn_ff[64+tid]; m=bn_ff[128+tid]; vv=bn_ff[192+tid];
        inv = g*rsqrtf(vv+BN_EPS);
        sc2s[tid]=inv; sh2s[tid]=(b_ff[tid]-m)*inv+bb;
    }
    for (int i = tid; i < 64*8; i += 256) {
        const int o = i>>3, seg = i&7;
        *(bf8*)&wf[o][seg*8] = *(const bf8*)&wb[47104 + o*64 + seg*8];
    }
    __syncthreads();
    for (int i = tid; i < 112*8; i += 256) {
        const int row = i>>3, seg = i&7;
        bf8 yv = {0,0,0,0,0,0,0,0}, zv = yv;
        if (row < 100) {
            const int q = q0 + row/25, v = row%25;
            yv = *(const bf8*)&Y[((size_t)n*3200 + q*25 + v)*64 + seg*8];
            const bf8 uv = *(const bf8*)&U[((size_t)(n*128+q)*25 + v)*64 + seg*8];
            #pragma unroll
            for (int j = 0; j < 8; ++j) {
                const int o = seg*8+j;
                zv[j] = f2bs(lrelu(b2f(yv[j]) + b2f(uv[j])*sc1s[o] + sh1s[o]));
            }
        }
        *(bf8*)&zs[row][seg*8] = yv;
        *(bf8*)&z1[row][seg*8] = zv;
    }
    __syncthreads();
    // GEMM: A = wff (m=o), B = z1 (n=px)
    const bf8 a0 = *(const bf8*)&wf[w*16+lr][lq*8];
    const bf8 a1 = *(const bf8*)&wf[w*16+lr][32+lq*8];
    for (int nt = 0; nt < 7; ++nt) {
        f4 acc = {0.f,0.f,0.f,0.f};
        const bf8 b0 = *(const bf8*)&z1[nt*16+lr][lq*8];
        const bf8 b1 = *(const bf8*)&z1[nt*16+lr][32+lq*8];
        acc = MFMA(a0,b0,acc); acc = MFMA(a1,b1,acc);
        const int px = nt*16+lr, o0 = w*16+lq*4;
        const s4 yr = *(const s4*)&zs[px][o0];
        const float r0 = lrelu(acc.x*sc2s[o0  ]+sh2s[o0  ]+b2f(yr.x));
        const float r1 = lrelu(acc.y*sc2s[o0+1]+sh2s[o0+1]+b2f(yr.y));
        const float r2 = lrelu(acc.z*sc2s[o0+2]+sh2s[o0+2]+b2f(yr.z));
        const float r3 = lrelu(acc.w*sc2s[o0+3]+sh2s[o0+3]+b2f(yr.w));
        *(s4*)&zout[px][o0] = packf4(r0,r1,r2,r3);
    }
    __syncthreads();
    for (int i = tid; i < 100*8; i += 256) {
        const int row = i>>3, seg = i&7;
        *(bf8*)&Y[((size_t)n*3200 + q0*25 + row)*64 + seg*8] = *(const bf8*)&zout[row][seg*8];
    }
}

// tcn: out[o][t][v] = lrelu(BN(sum_{dt,c} w[o][c][dt]*z[t+dt-3,v,c] + b) + z) f32
__global__ __launch_bounds__(256) void k_tcn(
    const short* __restrict__ Y, const short* __restrict__ wb,
    const float* __restrict__ b, const float* __restrict__ bn,
    float* __restrict__ out)
{
    const int n = blockIdx.x >> 5, tc = (blockIdx.x >> 1) & 15, oh = blockIdx.x & 1;
    const int t0 = tc*8;
    const int tid = threadIdx.x, w = tid>>6, lane = tid&63, lr = lane&15, lq = lane>>4;
    __shared__ short zs[352][72];
    __shared__ short wt[32][456];
    __shared__ short yout[208][40];
    __shared__ float scs[32], shs[32];
    if (tid < 32) {
        const int o = oh*32 + tid;
        const float g=bn[o], bb=bn[64+o], m=bn[128+o], vv=bn[192+o];
        const float inv = g*rsqrtf(vv+BN_EPS);
        scs[tid]=inv; shs[tid]=(b[o]-m)*inv+bb;
    }
    for (int i = tid; i < 352*8; i += 256) {
        const int row = i>>3, seg = i&7;
        bf8 val = {0,0,0,0,0,0,0,0};
        if (row < 350) {
            const int tlp = row/25, v = row%25, t = t0 - 3 + tlp;
            if (t >= 0 && t < 128)
                val = *(const bf8*)&Y[((size_t)n*3200 + t*25 + v)*64 + seg*8];
        }
        *(bf8*)&zs[row][seg*8] = val;
    }
    for (int i = tid; i < 32*57; i += 256) {
        const int o = i/57, seg = i%57;
        bf8 val = {0,0,0,0,0,0,0,0};
        if (seg < 56) val = *(const bf8*)&wb[51200 + (oh*32+o)*448 + seg*8];
        *(bf8*)&wt[o][seg*8] = val;
    }
    __syncthreads();
    // n-tiles (px): 13, split w:{w,w+4,w+8,(+12 if w==0)}
    for (int nn = 0; nn < 4; ++nn) {
        const int nt = w + nn*4;
        if (nt >= 13) break;
        for (int mt = 0; mt < 2; ++mt) {
            f4 acc = {0.f,0.f,0.f,0.f};
            for (int st = 0; st < 14; ++st) {
                const int dt = st>>1;
                const bf8 af = *(const bf8*)&wt[mt*16+lr][st*32+lq*8];
                const bf8 bf = *(const bf8*)&zs[nt*16 + lr + dt*25][(st&1)*32 + lq*8];
                acc = MFMA(af, bf, acc);
            }
            const int px = nt*16+lr, o0l = mt*16+lq*4;
            const s4 zr = *(const s4*)&zs[px+75][oh*32+o0l];
            const float r0 = lrelu(acc.x*scs[o0l  ]+shs[o0l  ]+b2f(zr.x));
            const float r1 = lrelu(acc.y*scs[o0l+1]+shs[o0l+1]+b2f(zr.y));
            const float r2 = lrelu(acc.z*scs[o0l+2]+shs[o0l+2]+b2f(zr.z));
            const float r3 = lrelu(acc.w*scs[o0l+3]+shs[o0l+3]+b2f(zr.w));
            *(s4*)&yout[px][o0l] = packf4(r0,r1,r2,r3);
        }
    }
    __syncthreads();
    for (int i = tid; i < 32*200; i += 256) {
        const int ol = i/200, p = i%200, tl = p/25, v = p%25;
        out[(size_t)n*204800 + (size_t)(oh*32+ol)*3200 + (t0+tl)*25 + v] = b2f(yout[p][ol]);
    }
}

// ---------------------------------------------------------------------------
extern "C" void kernel_launch(void* const* d_in, const int* in_sizes, int n_in,
                              void* d_out, int out_size, void* d_ws, size_t ws_size,
                              hipStream_t stream) {
    const float* x        = (const float*)d_in[0];
    const float* w_in_s   = (const float*)d_in[1];
    const float* b_in_s   = (const float*)d_in[2];
    const float* alphas   = (const float*)d_in[3];
    const float* att0s    = (const float*)d_in[4];
    const float* w_out_s  = (const float*)d_in[5];
    const float* b_out_s  = (const float*)d_in[6];
    const float* bn_out_s = (const float*)d_in[7];
    const float* w_ff_s   = (const float*)d_in[8];
    const float* b_ff_s   = (const float*)d_in[9];
    const float* bn_ff_s  = (const float*)d_in[10];
    const float* w_in_t   = (const float*)d_in[11];
    const float* b_in_t   = (const float*)d_in[12];
    const float* alphat_f = (const float*)d_in[13];
    const float* alphat_b = (const float*)d_in[14];
    const float* w_out_t  = (const float*)d_in[15];
    const float* b_out_t  = (const float*)d_in[16];
    const float* bn_out_t = (const float*)d_in[17];
    const float* w_ff_t   = (const float*)d_in[18];
    const float* b_ff_t   = (const float*)d_in[19];
    const float* bn_ff_t  = (const float*)d_in[20];
    const float* w_tcn    = (const float*)d_in[21];
    const float* b_tcn    = (const float*)d_in[22];
    const float* bn_tcn   = (const float*)d_in[23];
    float* out = (float*)d_out;
    char* ws = (char*)d_ws;

    short* wb    = (short*)(ws + 0);
    float* part  = (float*)(ws + 262144);
    short* attnB = (short*)(ws + 4102144);
    short* Y     = (short*)(ws + 4888576);
    short* aT    = (short*)(ws + 57317376);
    short* XB    = (short*)(ws + 74094592);           // phase 1
    short* QKT   = (short*)(ws + 74094592);           // phase 2 (XB dead)
    short* PT    = (short*)(ws + 74094592);           // phase 3 (QKT dead)
    short* U     = (short*)(ws + 74094592 + 52428800);

    k_prep<<<64, 256, 0, stream>>>(w_in_s, w_out_s, w_ff_s, w_in_t, w_out_t, w_ff_t, w_tcn, wb);
    k_x2b<<<2048, 256, 0, stream>>>(x, XB);
    k_attn_s_part<<<1536, 256, 0, stream>>>(x, w_in_s, b_in_s, part);
    k_attn_s_fin<<<1536, 256, 0, stream>>>(part, alphas, att0s, attnB);
    k_spatial<<<4096, 256, 0, stream>>>(XB, attnB, wb, b_out_s, bn_out_s, b_ff_s, bn_ff_s, Y);
    k_qkt<<<4096, 256, 0, stream>>>(Y, wb, b_in_t, QKT);
    k_score_t<<<512, 256, 0, stream>>>(QKT, alphat_f, alphat_b, aT);
    for (int ds = 0; ds < 4; ++ds) {
        k_pproj<<<1664, 256, 0, stream>>>(Y, wb, ds, PT);
        k_uacc<<<512, 256, 0, stream>>>(PT, aT, ds, ds ? 1 : 0, U);
    }
    k_temporal<<<4096, 256, 0, stream>>>(U, Y, wb, b_out_t, bn_out_t, b_ff_t, bn_ff_t);
    k_tcn<<<4096, 256, 0, stream>>>(Y, wb, b_tcn, bn_tcn, out);
}

// Round 4
// 1093.127 us; speedup vs baseline: 4.7565x; 1.3771x over previous
//
#include <hip/hip_runtime.h>
#include <math.h>

#define NN   128
#define TTc  128
#define VVc  25
#define TV   3200
#define BN_EPS 1e-5f

typedef __attribute__((ext_vector_type(8))) short bf8;   // 8 bf16 in 4 VGPRs
typedef __attribute__((ext_vector_type(4))) short s4;    // 4 bf16 (b64)
typedef __attribute__((ext_vector_type(4))) float f4;    // MFMA accumulator

#define MFMA(a,b,c) __builtin_amdgcn_mfma_f32_16x16x32_bf16(a,b,c,0,0,0)

__device__ __forceinline__ float lrelu(float a){ return a>=0.f ? a : 0.1f*a; }
__device__ __forceinline__ short f2bs(float f){
    union{float f; unsigned u;} x; x.f = f;
    unsigned r = x.u + 0x7FFF + ((x.u>>16)&1);
    return (short)(r>>16);
}
__device__ __forceinline__ float b2f(short s){
    union{unsigned u; float f;} x; x.u = ((unsigned)(unsigned short)s)<<16; return x.f;
}
__device__ __forceinline__ s4 packf4(float a,float b,float c,float d){
    s4 r; r.x=f2bs(a); r.y=f2bs(b); r.z=f2bs(c); r.w=f2bs(d); return r;
}

// ---------------------------------------------------------------------------
// Workspace layout unchanged from round 3 (total 178,952,192 B, proven OK):
//  wb bf16 weights       : byte 0
//  (former part region   : byte 262144 — now unused)
//  attnB bf16 [n][32v][96]: byte 4102144
//  Y  bf16 [n][3200][64] : byte 4888576
//  aT bf16 [n][4][q][t]  : byte 57317376
//  R  : byte 74094592 : XB -> QKT -> (PT | U)
// wb element offsets: w_in_s 0 [96][64]; w_out_s 6144 [64][192]; w_ff_s 18432
//  [64][64]; w_in_t 22528 [128][64]; w_out_t 30720 [64][256]; w_ff_t 47104
//  [64][64]; wt 51200 [64][448] (o, dt*64+c)
// ---------------------------------------------------------------------------

__global__ __launch_bounds__(256) void k_prep(
    const float* __restrict__ w_in_s, const float* __restrict__ w_out_s,
    const float* __restrict__ w_ff_s, const float* __restrict__ w_in_t,
    const float* __restrict__ w_out_t, const float* __restrict__ w_ff_t,
    const float* __restrict__ w_tcn, short* __restrict__ wb)
{
    const int total = 51200 + 64*448;
    for (int i = blockIdx.x*256 + threadIdx.x; i < total; i += gridDim.x*256) {
        float v;
        if      (i < 6144)  v = w_in_s[i];
        else if (i < 18432) v = w_out_s[i-6144];
        else if (i < 22528) v = w_ff_s[i-18432];
        else if (i < 30720) v = w_in_t[i-22528];
        else if (i < 47104) v = w_out_t[i-30720];
        else if (i < 51200) v = w_ff_t[i-47104];
        else { int j=i-51200; int o=j/448; int r=j%448; int dt=r>>6; int c=r&63;
               v = w_tcn[(o*64+c)*7 + dt]; }
        wb[i] = f2bs(v);
    }
}

// x f32 [n][c][t][v] -> XB bf16 pixel-major [n][t*25+v][64]
__global__ __launch_bounds__(256) void k_x2b(const float* __restrict__ x, short* __restrict__ XB)
{
    const int n = blockIdx.x >> 4, tc = blockIdx.x & 15, t0 = tc*8;
    const int tid = threadIdx.x;
    __shared__ float xs[64][201];
    const float* xb = x + (size_t)n*204800 + t0*25;
    for (int i = tid; i < 64*200; i += 256) { int c=i/200, p=i%200; xs[c][p] = xb[(size_t)c*3200 + p]; }
    __syncthreads();
    short* ob = XB + (size_t)n*204800 + t0*25*64;
    for (int i = tid; i < 200*64; i += 256) { int p=i>>6, c=i&63; ob[i] = f2bs(xs[c][p]); }
}

// ---------------------------------------------------------------------------
// Fused spatial attention scores (MFMA). grid = N*SS, 4 waves.
// Per chunk of 8 t's: stage XB->LDS; project q,k (32ch, K=64) into qkl[px][32];
// each wave accumulates one 16x16 tile of attn[u][v] over k=(t,c).
// Epilogue: tanh(acc/2048)*alpha + att0 -> attnB [n][32v][96] (pads zeroed).
// ---------------------------------------------------------------------------
__global__ __launch_bounds__(256) void k_attn_s(
    const short* __restrict__ XB, const short* __restrict__ wb,
    const float* __restrict__ b_in_s, const float* __restrict__ alphas,
    const float* __restrict__ att0s, short* __restrict__ attnB)
{
    const int n = blockIdx.x / 3, s = blockIdx.x % 3;
    const int tid = threadIdx.x, w = tid>>6, lane = tid&63, lr = lane&15, lq = lane>>4;
    __shared__ short ys[208][72];     // staged pixels [px][64c]
    __shared__ short qkl[208][40];    // projected [px][32ch]: 0-15 q, 16-31 k
    __shared__ short wsl[32][72];     // weight rows (q 16 + k 16) x 64c
    __shared__ float bl[32];

    for (int i = tid; i < 32*8; i += 256) {
        const int cl = i>>3, seg = i&7;
        const int row = (cl < 16) ? (s*16 + cl) : (48 + s*16 + (cl-16));
        *(bf8*)&wsl[cl][seg*8] = *(const bf8*)&wb[row*64 + seg*8];
    }
    if (tid < 32) {
        const int row = (tid < 16) ? (s*16 + tid) : (48 + s*16 + (tid-16));
        bl[tid] = b_in_s[row];
    }

    const int mt = w>>1, sn = w&1;     // this wave's score tile (u-tile, v-tile)
    f4 acc = {0.f,0.f,0.f,0.f};

    for (int ch = 0; ch < 16; ++ch) {
        __syncthreads();   // qkl/ys from prev iter fully consumed
        for (int i = tid; i < 208*8; i += 256) {
            const int row = i>>3, seg = i&7;
            bf8 val = {0,0,0,0,0,0,0,0};
            if (row < 200)
                val = *(const bf8*)&XB[((size_t)n*3200 + ch*200 + row)*64 + seg*8];
            *(bf8*)&ys[row][seg*8] = val;
        }
        __syncthreads();
        // projection: wave w covers px-tiles {w, w+4, w+8, w+12}
        for (int nn = 0; nn < 4; ++nn) {
            const int nt2 = w + nn*4;
            if (nt2 >= 13) break;
            const bf8 b0 = *(const bf8*)&ys[nt2*16+lr][lq*8];
            const bf8 b1 = *(const bf8*)&ys[nt2*16+lr][32+lq*8];
            for (int mt2 = 0; mt2 < 2; ++mt2) {
                f4 pa = {0.f,0.f,0.f,0.f};
                const bf8 a0 = *(const bf8*)&wsl[mt2*16+lr][lq*8];
                const bf8 a1 = *(const bf8*)&wsl[mt2*16+lr][32+lq*8];
                pa = MFMA(a0,b0,pa); pa = MFMA(a1,b1,pa);
                const int px = nt2*16+lr, c0 = mt2*16+lq*4;
                *(s4*)&qkl[px][c0] =
                    packf4(pa.x+bl[c0], pa.y+bl[c0+1], pa.z+bl[c0+2], pa.w+bl[c0+3]);
            }
        }
        __syncthreads();
        // score accumulate: k = (t_local, c), 4 steps of 32
        for (int ks = 0; ks < 4; ++ks) {
            const int tl = ks*2 + (lq>>1);
            const bf8 af = *(const bf8*)&qkl[tl*25 + mt*16+lr][(lq&1)*8];
            const bf8 bf = *(const bf8*)&qkl[tl*25 + sn*16+lr][16 + (lq&1)*8];
            acc = MFMA(af, bf, acc);
        }
    }
    const float alpha = alphas[s];
    const int v = sn*16 + lr, u0 = mt*16 + lq*4;
    float r[4];
    #pragma unroll
    for (int j = 0; j < 4; ++j) {
        const int u = u0 + j;
        const float a = (j==0)?acc.x:((j==1)?acc.y:((j==2)?acc.z:acc.w));
        r[j] = (u < 25 && v < 25)
             ? tanhf(a*(1.f/2048.f))*alpha + att0s[s*625 + u*25 + v] : 0.f;
    }
    *(s4*)&attnB[(size_t)n*3072 + v*96 + s*32 + u0] = packf4(r[0],r[1],r[2],r[3]);
}

// ---------------------------------------------------------------------------
// fused spatial block (MFMA). block=(n, t-chunk4), wave w owns t=t0+w.
// ---------------------------------------------------------------------------
__global__ __launch_bounds__(256) void k_spatial(
    const short* __restrict__ XB, const short* __restrict__ attnB, const short* __restrict__ wb,
    const float* __restrict__ b_out, const float* __restrict__ bn_out,
    const float* __restrict__ b_ff,  const float* __restrict__ bn_ff,
    short* __restrict__ Y)
{
    const int n = blockIdx.x >> 5, tc = blockIdx.x & 31, t0 = tc*4;
    const int tid = threadIdx.x;
    const int w = tid>>6, lane = tid&63, lr = lane&15, lq = lane>>4;
    __shared__ short xs[4][32][72];
    __shared__ short wlo[64][200];
    __shared__ short wlf[64][72];
    __shared__ short ab[32][104];
    __shared__ short gsT[4][64][104];
    __shared__ short y1[4][32][72];
    __shared__ float sc1s[64], sh1s[64], sc2s[64], sh2s[64];

    for (int i = tid; i < 4*32*8; i += 256) {
        const int row = i>>3, seg = i&7, tl = row>>5, uv = row&31;
        bf8 val = {0,0,0,0,0,0,0,0};
        if (uv < 25) val = *(const bf8*)&XB[((size_t)n*3200 + (t0+tl)*25 + uv)*64 + seg*8];
        *(bf8*)&xs[tl][uv][seg*8] = val;
    }
    for (int i = tid; i < 64*24; i += 256) {
        const int o = i/24, seg = i%24;
        *(bf8*)&wlo[o][seg*8] = *(const bf8*)&wb[6144 + o*192 + seg*8];
    }
    for (int i = tid; i < 64*8; i += 256) {
        const int o = i>>3, seg = i&7;
        *(bf8*)&wlf[o][seg*8] = *(const bf8*)&wb[18432 + o*64 + seg*8];
    }
    for (int i = tid; i < 32*12; i += 256) {
        const int v = i/12, seg = i%12;
        *(bf8*)&ab[v][seg*8] = *(const bf8*)&attnB[(size_t)n*3072 + v*96 + seg*8];
    }
    if (tid < 64) {
        float g=bn_out[tid], bb=bn_out[64+tid], m=bn_out[128+tid], vv=bn_out[192+tid];
        float inv = g*rsqrtf(vv+BN_EPS);
        sc1s[tid]=inv; sh1s[tid]=(b_out[tid]-m)*inv+bb;
        g=bn_ff[tid]; bb=bn_ff[64+tid]; m=bn_ff[128+tid]; vv=bn_ff[192+tid];
        inv = g*rsqrtf(vv+BN_EPS);
        sc2s[tid]=inv; sh2s[tid]=(b_ff[tid]-m)*inv+bb;
    }
    __syncthreads();

    const int t = t0 + w;
    for (int s = 0; s < 3; ++s) {
        for (int mt = 0; mt < 2; ++mt) {
            const bf8 a0 = *(const bf8*)&xs[w][mt*16+lr][lq*8];
            const bf8 a1 = *(const bf8*)&xs[w][mt*16+lr][32+lq*8];
            for (int nt = 0; nt < 4; ++nt) {
                f4 acc = {0.f,0.f,0.f,0.f};
                const bf8 b0 = *(const bf8*)&wlo[nt*16+lr][s*64 + lq*8];
                const bf8 b1 = *(const bf8*)&wlo[nt*16+lr][s*64 + 32 + lq*8];
                acc = MFMA(a0,b0,acc); acc = MFMA(a1,b1,acc);
                const int o = nt*16+lr, u0 = mt*16+lq*4;
                *(s4*)&gsT[w][o][s*32+u0] = packf4(acc.x,acc.y,acc.z,acc.w);
            }
        }
    }
    for (int mt = 0; mt < 4; ++mt) {
        const bf8 a0 = *(const bf8*)&gsT[w][mt*16+lr][lq*8];
        const bf8 a1 = *(const bf8*)&gsT[w][mt*16+lr][32+lq*8];
        const bf8 a2 = *(const bf8*)&gsT[w][mt*16+lr][64+lq*8];
        for (int nt = 0; nt < 2; ++nt) {
            f4 acc = {0.f,0.f,0.f,0.f};
            const bf8 b0 = *(const bf8*)&ab[nt*16+lr][lq*8];
            const bf8 b1 = *(const bf8*)&ab[nt*16+lr][32+lq*8];
            const bf8 b2 = *(const bf8*)&ab[nt*16+lr][64+lq*8];
            acc = MFMA(a0,b0,acc); acc = MFMA(a1,b1,acc); acc = MFMA(a2,b2,acc);
            const int v = nt*16+lr, o0 = mt*16+lq*4;
            const s4 xr = *(const s4*)&xs[w][v][o0];
            const float r0 = lrelu(acc.x*sc1s[o0  ]+sh1s[o0  ]+b2f(xr.x));
            const float r1 = lrelu(acc.y*sc1s[o0+1]+sh1s[o0+1]+b2f(xr.y));
            const float r2 = lrelu(acc.z*sc1s[o0+2]+sh1s[o0+2]+b2f(xr.z));
            const float r3 = lrelu(acc.w*sc1s[o0+3]+sh1s[o0+3]+b2f(xr.w));
            *(s4*)&y1[w][v][o0] = packf4(r0,r1,r2,r3);
        }
    }
    for (int mt = 0; mt < 4; ++mt) {
        const bf8 a0 = *(const bf8*)&wlf[mt*16+lr][lq*8];
        const bf8 a1 = *(const bf8*)&wlf[mt*16+lr][32+lq*8];
        for (int nt = 0; nt < 2; ++nt) {
            f4 acc = {0.f,0.f,0.f,0.f};
            const bf8 b0 = *(const bf8*)&y1[w][nt*16+lr][lq*8];
            const bf8 b1 = *(const bf8*)&y1[w][nt*16+lr][32+lq*8];
            acc = MFMA(a0,b0,acc); acc = MFMA(a1,b1,acc);
            const int v = nt*16+lr, o0 = mt*16+lq*4;
            if (v < 25) {
                const s4 xr = *(const s4*)&xs[w][v][o0];
                const float r0 = lrelu(acc.x*sc2s[o0  ]+sh2s[o0  ]+b2f(xr.x));
                const float r1 = lrelu(acc.y*sc2s[o0+1]+sh2s[o0+1]+b2f(xr.y));
                const float r2 = lrelu(acc.z*sc2s[o0+2]+sh2s[o0+2]+b2f(xr.z));
                const float r3 = lrelu(acc.w*sc2s[o0+3]+sh2s[o0+3]+b2f(xr.w));
                *(s4*)&Y[((size_t)n*3200 + t*25 + v)*64 + o0] = packf4(r0,r1,r2,r3);
            }
        }
    }
}

// temporal q/k proj -> QKT bf16 [n][t][128oc][25v]
__global__ __launch_bounds__(256) void k_qkt(
    const short* __restrict__ Y, const short* __restrict__ wb,
    const float* __restrict__ b_in_t, short* __restrict__ qkt)
{
    const int n = blockIdx.x >> 5, tc = blockIdx.x & 31, t0 = tc*4;
    const int tid = threadIdx.x;
    const int w = tid>>6, lane = tid&63, lr = lane&15, lq = lane>>4;
    __shared__ short ys[4][32][72];
    __shared__ short wi[128][72];
    for (int i = tid; i < 4*32*8; i += 256) {
        const int row = i>>3, seg = i&7, tl = row>>5, v = row&31;
        bf8 val = {0,0,0,0,0,0,0,0};
        if (v < 25) val = *(const bf8*)&Y[((size_t)n*3200 + (t0+tl)*25 + v)*64 + seg*8];
        *(bf8*)&ys[tl][v][seg*8] = val;
    }
    for (int i = tid; i < 128*8; i += 256) {
        const int o = i>>3, seg = i&7;
        *(bf8*)&wi[o][seg*8] = *(const bf8*)&wb[22528 + o*64 + seg*8];
    }
    __syncthreads();
    for (int mi = 0; mi < 2; ++mi) {
        const int mt = w*2+mi, tl = mt>>1, vh = mt&1;
        const bf8 a0 = *(const bf8*)&ys[tl][vh*16+lr][lq*8];
        const bf8 a1 = *(const bf8*)&ys[tl][vh*16+lr][32+lq*8];
        for (int nt = 0; nt < 8; ++nt) {
            f4 acc = {0.f,0.f,0.f,0.f};
            const bf8 b0 = *(const bf8*)&wi[nt*16+lr][lq*8];
            const bf8 b1 = *(const bf8*)&wi[nt*16+lr][32+lq*8];
            acc = MFMA(a0,b0,acc); acc = MFMA(a1,b1,acc);
            const int oc = nt*16+lr, v0 = vh*16+lq*4, t = t0+tl;
            const float bias = b_in_t[oc];
            const size_t base = (size_t)n*409600 + (size_t)t*3200 + oc*25 + v0;
            if (v0 < 24)
                *(s4*)&qkt[base] = packf4(acc.x+bias, acc.y+bias, acc.z+bias, acc.w+bias);
            else if (v0 == 24)
                qkt[base] = f2bs(acc.x+bias);
        }
    }
}

// temporal scores -> aT bf16 [n][ds][q][t] (zeros in masked region)
__global__ __launch_bounds__(256) void k_score_t(
    const short* __restrict__ qkt, const float* __restrict__ alphat_f,
    const float* __restrict__ alphat_b, short* __restrict__ aT)
{
    const int n = blockIdx.x >> 2, ds = blockIdx.x & 3, dir = ds>>1, s = ds&1;
    const int qoff = dir*32 + s*16, koff = 64 + dir*32 + s*16;
    const float alpha = dir ? alphat_b[s] : alphat_f[s];
    const int tid = threadIdx.x, w = tid>>6, lane = tid&63, lr = lane&15, lq = lane>>4;
    const short* qb = qkt + (size_t)n*409600;
    short* ao = aT + (size_t)(n*4+ds)*16384;
    const bf8 zf = {0,0,0,0,0,0,0,0};
    for (int ni = 0; ni < 2; ++ni) {
        const int nt = w*2+ni;
        for (int mt = 0; mt < 8; ++mt) {
            const int q = nt*16+lr, t0r = mt*16+lq*4;
            const bool skip = (dir==0) ? (mt < nt) : (mt > nt);
            if (skip) { s4 z = {0,0,0,0}; *(s4*)&ao[q*128 + t0r] = z; continue; }
            f4 acc = {0.f,0.f,0.f,0.f};
            for (int ks = 0; ks < 13; ++ks) {
                bf8 af, bf;
                if (ks==12 && lq>=2) { af = zf; bf = zf; }
                else {
                    af = *(const bf8*)&qb[(size_t)(mt*16+lr)*3200 + qoff*25 + ks*32 + lq*8];
                    bf = *(const bf8*)&qb[(size_t)(nt*16+lr)*3200 + koff*25 + ks*32 + lq*8];
                }
                acc = MFMA(af, bf, acc);
            }
            float r[4];
            #pragma unroll
            for (int j = 0; j < 4; ++j) {
                const int tt = t0r + j;
                const bool ok = (dir==0) ? (tt >= q) : (tt <= q);
                const float a = (j==0)?acc.x:((j==1)?acc.y:((j==2)?acc.z:acc.w));
                r[j] = ok ? tanhf(a*(1.f/400.f))*alpha : 0.f;
            }
            *(s4*)&ao[q*128 + t0r] = packf4(r[0],r[1],r[2],r[3]);
        }
    }
}

// pproj (per ds): PT[v][o][t] = sum_c Y[t,v,c]*w_out_t[o][ds*64+c]
__global__ __launch_bounds__(256) void k_pproj(
    const short* __restrict__ Y, const short* __restrict__ wb,
    int ds, short* __restrict__ PT)
{
    const int n = blockIdx.x / 13, vb = blockIdx.x % 13, v0 = vb*2;
    const int tid = threadIdx.x, w = tid>>6, lane = tid&63, lr = lane&15, lq = lane>>4;
    __shared__ short ys[2][128][72];
    __shared__ short wo[64][72];
    for (int i = tid; i < 2*128*8; i += 256) {
        const int row = i>>3, seg = i&7, vl = row>>7, t = row&127, v = v0+vl;
        bf8 val = {0,0,0,0,0,0,0,0};
        if (v < 25) val = *(const bf8*)&Y[((size_t)n*3200 + t*25 + v)*64 + seg*8];
        *(bf8*)&ys[vl][t][seg*8] = val;
    }
    for (int i = tid; i < 64*8; i += 256) {
        const int o = i>>3, seg = i&7;
        *(bf8*)&wo[o][seg*8] = *(const bf8*)&wb[30720 + o*256 + ds*64 + seg*8];
    }
    __syncthreads();
    for (int mi = 0; mi < 4; ++mi) {
        const int mt = w*4+mi, vl = mt>>3, tt = mt&7;
        const bf8 a0 = *(const bf8*)&ys[vl][tt*16+lr][lq*8];
        const bf8 a1 = *(const bf8*)&ys[vl][tt*16+lr][32+lq*8];
        for (int nt = 0; nt < 4; ++nt) {
            f4 acc = {0.f,0.f,0.f,0.f};
            const bf8 b0 = *(const bf8*)&wo[nt*16+lr][lq*8];
            const bf8 b1 = *(const bf8*)&wo[nt*16+lr][32+lq*8];
            acc = MFMA(a0,b0,acc); acc = MFMA(a1,b1,acc);
            const int o = nt*16+lr, t0r = tt*16+lq*4, v = v0+vl;
            if (v < 25)
                *(s4*)&PT[((size_t)(n*25+v)*64 + o)*128 + t0r] = packf4(acc.x,acc.y,acc.z,acc.w);
        }
    }
}

// uacc (per ds): U[q][v][o] (+)= sum_t PT[v][o][t]*aT[q][t]   (bf16 RMW)
__global__ __launch_bounds__(256) void k_uacc(
    const short* __restrict__ PT, const short* __restrict__ aT,
    int ds, int beta, short* __restrict__ U)
{
    const int n = blockIdx.x >> 2, Q = blockIdx.x & 3;
    const int dir = ds >> 1;
    const int tid = threadIdx.x, w = tid>>6, lane = tid&63, lr = lane&15, lq = lane>>4;
    __shared__ short pts[400][136];
    __shared__ short ats[128][136];
    for (int i = tid; i < 400*16; i += 256) {
        const int r = i>>4, seg = i&15;
        *(bf8*)&pts[r][seg*8] =
            *(const bf8*)&PT[((size_t)n*1600 + Q*400 + r)*128 + seg*8];
    }
    for (int i = tid; i < 128*16; i += 256) {
        const int q = i>>4, seg = i&15;
        *(bf8*)&ats[q][seg*8] =
            *(const bf8*)&aT[(size_t)(n*4+ds)*16384 + q*128 + seg*8];
    }
    __syncthreads();
    const int m_lo = w*7, m_hi = (m_lo+7 < 25) ? m_lo+7 : 25;
    for (int mt = m_lo; mt < m_hi; ++mt) {
        for (int nt = 0; nt < 8; ++nt) {
            f4 acc = {0.f,0.f,0.f,0.f};
            for (int ks = 0; ks < 4; ++ks) {
                const bool skip = (dir==0) ? (ks*32+31 < nt*16) : (ks*32 > nt*16+15);
                if (skip) continue;
                const bf8 af = *(const bf8*)&pts[mt*16+lr][ks*32+lq*8];
                const bf8 bf = *(const bf8*)&ats[nt*16+lr][ks*32+lq*8];
                acc = MFMA(af, bf, acc);
            }
            const int q = nt*16+lr, m0 = mt*16+lq*4;
            const int gr = Q*400 + m0, v = gr>>6, o0 = gr&63;
            short* dst = U + ((size_t)(n*128+q)*25 + v)*64 + o0;
            if (beta) {
                const s4 old = *(const s4*)dst;
                acc.x += b2f(old.x); acc.y += b2f(old.y);
                acc.z += b2f(old.z); acc.w += b2f(old.w);
            }
            *(s4*)dst = packf4(acc.x,acc.y,acc.z,acc.w);
        }
    }
}

// temporal ff block: z1 = lrelu(y + u*sc1+sh1); Y = lrelu(y + BN(Wff@z1)) in-place
__global__ __launch_bounds__(256) void k_temporal(
    const short* __restrict__ U, short* __restrict__ Y, const short* __restrict__ wb,
    const float* __restrict__ b_out, const float* __restrict__ bn_out,
    const float* __restrict__ b_ff,  const float* __restrict__ bn_ff)
{
    const int n = blockIdx.x >> 5, qc = blockIdx.x & 31, q0 = qc*4;
    const int tid = threadIdx.x, w = tid>>6, lane = tid&63, lr = lane&15, lq = lane>>4;
    __shared__ short zs[112][72];
    __shared__ short z1[112][72];
    __shared__ short zout[112][72];
    __shared__ short wf[64][72];
    __shared__ float sc1s[64], sh1s[64], sc2s[64], sh2s[64];
    if (tid < 64) {
        float g=bn_out[tid], bb=bn_out[64+tid], m=bn_out[128+tid], vv=bn_out[192+tid];
        float inv = g*rsqrtf(vv+BN_EPS);
        sc1s[tid]=inv; sh1s[tid]=(b_out[tid]-m)*inv+bb;
        g=bn_ff[tid]; bb=bn_ff[64+tid]; m=bn_ff[128+tid]; vv=bn_ff[192+tid];
        inv = g*rsqrtf(vv+BN_EPS);
        sc2s[tid]=inv; sh2s[tid]=(b_ff[tid]-m)*inv+bb;
    }
    for (int i = tid; i < 64*8; i += 256) {
        const int o = i>>3, seg = i&7;
        *(bf8*)&wf[o][seg*8] = *(const bf8*)&wb[47104 + o*64 + seg*8];
    }
    __syncthreads();
    for (int i = tid; i < 112*8; i += 256) {
        const int row = i>>3, seg = i&7;
        bf8 yv = {0,0,0,0,0,0,0,0}, zv = yv;
        if (row < 100) {
            const int q = q0 + row/25, v = row%25;
            yv = *(const bf8*)&Y[((size_t)n*3200 + q*25 + v)*64 + seg*8];
            const bf8 uv = *(const bf8*)&U[((size_t)(n*128+q)*25 + v)*64 + seg*8];
            #pragma unroll
            for (int j = 0; j < 8; ++j) {
                const int o = seg*8+j;
                zv[j] = f2bs(lrelu(b2f(yv[j]) + b2f(uv[j])*sc1s[o] + sh1s[o]));
            }
        }
        *(bf8*)&zs[row][seg*8] = yv;
        *(bf8*)&z1[row][seg*8] = zv;
    }
    __syncthreads();
    const bf8 a0 = *(const bf8*)&wf[w*16+lr][lq*8];
    const bf8 a1 = *(const bf8*)&wf[w*16+lr][32+lq*8];
    for (int nt = 0; nt < 7; ++nt) {
        f4 acc = {0.f,0.f,0.f,0.f};
        const bf8 b0 = *(const bf8*)&z1[nt*16+lr][lq*8];
        const bf8 b1 = *(const bf8*)&z1[nt*16+lr][32+lq*8];
        acc = MFMA(a0,b0,acc); acc = MFMA(a1,b1,acc);
        const int px = nt*16+lr, o0 = w*16+lq*4;
        const s4 yr = *(const s4*)&zs[px][o0];
        const float r0 = lrelu(acc.x*sc2s[o0  ]+sh2s[o0  ]+b2f(yr.x));
        const float r1 = lrelu(acc.y*sc2s[o0+1]+sh2s[o0+1]+b2f(yr.y));
        const float r2 = lrelu(acc.z*sc2s[o0+2]+sh2s[o0+2]+b2f(yr.z));
        const float r3 = lrelu(acc.w*sc2s[o0+3]+sh2s[o0+3]+b2f(yr.w));
        *(s4*)&zout[px][o0] = packf4(r0,r1,r2,r3);
    }
    __syncthreads();
    for (int i = tid; i < 100*8; i += 256) {
        const int row = i>>3, seg = i&7;
        *(bf8*)&Y[((size_t)n*3200 + q0*25 + row)*64 + seg*8] = *(const bf8*)&zout[row][seg*8];
    }
}

// tcn: out[o][t][v] = lrelu(BN(sum_{dt,c} w[o][c][dt]*z[t+dt-3,v,c] + b) + z) f32
__global__ __launch_bounds__(256) void k_tcn(
    const short* __restrict__ Y, const short* __restrict__ wb,
    const float* __restrict__ b, const float* __restrict__ bn,
    float* __restrict__ out)
{
    const int n = blockIdx.x >> 5, tc = (blockIdx.x >> 1) & 15, oh = blockIdx.x & 1;
    const int t0 = tc*8;
    const int tid = threadIdx.x, w = tid>>6, lane = tid&63, lr = lane&15, lq = lane>>4;
    __shared__ short zs[352][72];
    __shared__ short wt[32][456];
    __shared__ short yout[208][40];
    __shared__ float scs[32], shs[32];
    if (tid < 32) {
        const int o = oh*32 + tid;
        const float g=bn[o], bb=bn[64+o], m=bn[128+o], vv=bn[192+o];
        const float inv = g*rsqrtf(vv+BN_EPS);
        scs[tid]=inv; shs[tid]=(b[o]-m)*inv+bb;
    }
    for (int i = tid; i < 352*8; i += 256) {
        const int row = i>>3, seg = i&7;
        bf8 val = {0,0,0,0,0,0,0,0};
        if (row < 350) {
            const int tlp = row/25, v = row%25, t = t0 - 3 + tlp;
            if (t >= 0 && t < 128)
                val = *(const bf8*)&Y[((size_t)n*3200 + t*25 + v)*64 + seg*8];
        }
        *(bf8*)&zs[row][seg*8] = val;
    }
    for (int i = tid; i < 32*57; i += 256) {
        const int o = i/57, seg = i%57;
        bf8 val = {0,0,0,0,0,0,0,0};
        if (seg < 56) val = *(const bf8*)&wb[51200 + (oh*32+o)*448 + seg*8];
        *(bf8*)&wt[o][seg*8] = val;
    }
    __syncthreads();
    for (int nn = 0; nn < 4; ++nn) {
        const int nt = w + nn*4;
        if (nt >= 13) break;
        for (int mt = 0; mt < 2; ++mt) {
            f4 acc = {0.f,0.f,0.f,0.f};
            for (int st = 0; st < 14; ++st) {
                const int dt = st>>1;
                const bf8 af = *(const bf8*)&wt[mt*16+lr][st*32+lq*8];
                const bf8 bf = *(const bf8*)&zs[nt*16 + lr + dt*25][(st&1)*32 + lq*8];
                acc = MFMA(af, bf, acc);
            }
            const int px = nt*16+lr, o0l = mt*16+lq*4;
            const s4 zr = *(const s4*)&zs[px+75][oh*32+o0l];
            const float r0 = lrelu(acc.x*scs[o0l  ]+shs[o0l  ]+b2f(zr.x));
            const float r1 = lrelu(acc.y*scs[o0l+1]+shs[o0l+1]+b2f(zr.y));
            const float r2 = lrelu(acc.z*scs[o0l+2]+shs[o0l+2]+b2f(zr.z));
            const float r3 = lrelu(acc.w*scs[o0l+3]+shs[o0l+3]+b2f(zr.w));
            *(s4*)&yout[px][o0l] = packf4(r0,r1,r2,r3);
        }
    }
    __syncthreads();
    for (int i = tid; i < 32*200; i += 256) {
        const int ol = i/200, p = i%200, tl = p/25, v = p%25;
        out[(size_t)n*204800 + (size_t)(oh*32+ol)*3200 + (t0+tl)*25 + v] = b2f(yout[p][ol]);
    }
}

// ---------------------------------------------------------------------------
extern "C" void kernel_launch(void* const* d_in, const int* in_sizes, int n_in,
                              void* d_out, int out_size, void* d_ws, size_t ws_size,
                              hipStream_t stream) {
    const float* x        = (const float*)d_in[0];
    const float* w_in_s   = (const float*)d_in[1];
    const float* b_in_s   = (const float*)d_in[2];
    const float* alphas   = (const float*)d_in[3];
    const float* att0s    = (const float*)d_in[4];
    const float* w_out_s  = (const float*)d_in[5];
    const float* b_out_s  = (const float*)d_in[6];
    const float* bn_out_s = (const float*)d_in[7];
    const float* w_ff_s   = (const float*)d_in[8];
    const float* b_ff_s   = (const float*)d_in[9];
    const float* bn_ff_s  = (const float*)d_in[10];
    const float* w_in_t   = (const float*)d_in[11];
    const float* b_in_t   = (const float*)d_in[12];
    const float* alphat_f = (const float*)d_in[13];
    const float* alphat_b = (const float*)d_in[14];
    const float* w_out_t  = (const float*)d_in[15];
    const float* b_out_t  = (const float*)d_in[16];
    const float* bn_out_t = (const float*)d_in[17];
    const float* w_ff_t   = (const float*)d_in[18];
    const float* b_ff_t   = (const float*)d_in[19];
    const float* bn_ff_t  = (const float*)d_in[20];
    const float* w_tcn    = (const float*)d_in[21];
    const float* b_tcn    = (const float*)d_in[22];
    const float* bn_tcn   = (const float*)d_in[23];
    float* out = (float*)d_out;
    char* ws = (char*)d_ws;

    short* wb    = (short*)(ws + 0);
    short* attnB = (short*)(ws + 4102144);
    short* Y     = (short*)(ws + 4888576);
    short* aT    = (short*)(ws + 57317376);
    short* XB    = (short*)(ws + 74094592);           // phase 1
    short* QKT   = (short*)(ws + 74094592);           // phase 2 (XB dead)
    short* PT    = (short*)(ws + 74094592);           // phase 3 (QKT dead)
    short* U     = (short*)(ws + 74094592 + 52428800);

    k_prep<<<64, 256, 0, stream>>>(w_in_s, w_out_s, w_ff_s, w_in_t, w_out_t, w_ff_t, w_tcn, wb);
    k_x2b<<<2048, 256, 0, stream>>>(x, XB);
    k_attn_s<<<NN * 3, 256, 0, stream>>>(XB, wb, b_in_s, alphas, att0s, attnB);
    k_spatial<<<4096, 256, 0, stream>>>(XB, attnB, wb, b_out_s, bn_out_s, b_ff_s, bn_ff_s, Y);
    k_qkt<<<4096, 256, 0, stream>>>(Y, wb, b_in_t, QKT);
    k_score_t<<<512, 256, 0, stream>>>(QKT, alphat_f, alphat_b, aT);
    for (int ds = 0; ds < 4; ++ds) {
        k_pproj<<<1664, 256, 0, stream>>>(Y, wb, ds, PT);
        k_uacc<<<512, 256, 0, stream>>>(PT, aT, ds, ds ? 1 : 0, U);
    }
    k_temporal<<<4096, 256, 0, stream>>>(U, Y, wb, b_out_t, bn_out_t, b_ff_t, bn_ff_t);
    k_tcn<<<4096, 256, 0, stream>>>(Y, wb, b_tcn, bn_tcn, out);
}